// Round 4
// baseline (1267.621 us; speedup 1.0000x reference)
//
#include <hip/hip_runtime.h>
#include <math.h>

// ---------------- problem constants ----------------
#define C_    256
#define NTOK  65536   // B * 64 * 64

// LDS sizes (bytes)
#define ATTN_LDS (64*72*2*4)   // qm,km,vT,Pm : 36,864
#define PROJ_LDS (16*264*4)    // outT        : 16,896
#define MLP_LDS  (32*1032*2)   // hid (outT overlays) : 66,048

typedef __bf16 bf16x8 __attribute__((ext_vector_type(8)));
typedef float  f32x4  __attribute__((ext_vector_type(4)));
#define MFMA16(a,b,c) __builtin_amdgcn_mfma_f32_16x16x32_bf16((a),(b),(c),0,0,0)

__device__ inline ushort f2b(float f) {
    unsigned u = __builtin_bit_cast(unsigned, f);
    return (ushort)((u + 0x7fffu + ((u >> 16) & 1u)) >> 16);   // RNE
}

union BF8u { ushort u[8]; bf16x8 v; };
__device__ inline bf16x8 cvt8(float4 a, float4 b) {
    BF8u t;
    t.u[0] = f2b(a.x); t.u[1] = f2b(a.y); t.u[2] = f2b(a.z); t.u[3] = f2b(a.w);
    t.u[4] = f2b(b.x); t.u[5] = f2b(b.y); t.u[6] = f2b(b.z); t.u[7] = f2b(b.w);
    return t.v;
}

// ---------------- f32 -> bf16 weight conversion ----------------
__global__ void f2b_kernel(ushort* __restrict__ dst, const float* __restrict__ src) {
    size_t i = ((size_t)blockIdx.x * 256 + threadIdx.x) * 4;
    float4 v = *reinterpret_cast<const float4*>(src + i);
    ushort4 u = { f2b(v.x), f2b(v.y), f2b(v.z), f2b(v.w) };
    *reinterpret_cast<ushort4*>(dst + i) = u;
}

// ---------------- continuous position bias table ----------------
__global__ void cpb_kernel(const float* __restrict__ w1, const float* __restrict__ b1,
                           const float* __restrict__ w2, float* __restrict__ biastab) {
    __shared__ float red[256];
    const int e = blockIdx.x;
    const int t = threadIdx.x;
    const int p = e / 15, q = e % 15;
    const float v0 = (float)(p - 7) * (8.0f / 7.0f);
    const float v1 = (float)(q - 7) * (8.0f / 7.0f);
    const float t0 = copysignf(log2f(fabsf(v0) + 1.0f) * (1.0f / 3.0f), v0);
    const float t1 = copysignf(log2f(fabsf(v1) + 1.0f) * (1.0f / 3.0f), v1);
    const float ha = fmaxf(0.0f, t0 * w1[t * 2]         + t1 * w1[t * 2 + 1]         + b1[t]);
    const float hb = fmaxf(0.0f, t0 * w1[(t + 256) * 2] + t1 * w1[(t + 256) * 2 + 1] + b1[t + 256]);
    for (int h = 0; h < 8; ++h) {
        __syncthreads();
        red[t] = ha * w2[h * 512 + t] + hb * w2[h * 512 + t + 256];
        __syncthreads();
        for (int s = 128; s > 0; s >>= 1) {
            if (t < s) red[t] += red[t + s];
            __syncthreads();
        }
        if (t == 0) biastab[e * 8 + h] = 16.0f / (1.0f + expf(-red[0]));
    }
}

// ---------------- expand bias to [8][64][64] ----------------
__global__ void biasx_kernel(const float* __restrict__ biastab, float* __restrict__ biasx) {
    int h = blockIdx.x >> 6, n = blockIdx.x & 63, m = threadIdx.x;
    int idx = ((n >> 3) - (m >> 3) + 7) * 15 + ((n & 7) - (m & 7) + 7);
    biasx[((size_t)(h * 64 + n)) * 64 + m] = biastab[idx * 8 + h];
}

// ---------------- fused window attention (bf16 MFMA, head pairs) ----------------
// one block per window, 4 waves; wave w owns token rows [w*16, w*16+16)
__global__ __launch_bounds__(256, 4) void attn_mfma_kernel(
    const float* __restrict__ x, const ushort* __restrict__ qwb,
    const float* __restrict__ qb, const float* __restrict__ lsc,
    const float* __restrict__ biasx, ushort* __restrict__ ao, int shift)
{
    extern __shared__ ushort sm[];
    ushort* qm = sm;              // [64][72]  token-major q (2 heads: cols p*32..)
    ushort* km = sm + 64 * 72;    // [64][72]
    ushort* vT = km + 64 * 72;    // [64][72]  rows = p*32+chan, cols = token
    ushort* Pm = vT + 64 * 72;    // [64][72]  (own-wave rows only -> single buffer)

    const int t   = threadIdx.x;
    const int win = blockIdx.x;
    const int b = win >> 6, wh = (win >> 3) & 7, ww = win & 7;
    const int w = t >> 6, l = t & 63, lr = l & 15, lg = l >> 4;
    const int wtile = w * 16;
    const int tokr0 = wtile + lg * 4;
    const f32x4 zf = { 0.f, 0.f, 0.f, 0.f };

    // ---- A fragments straight from global (rolled), f32 -> bf16 ----
    bf16x8 af[8];
    {
        int n = wtile + lr, i = n >> 3, j = n & 7;
        int rr = (wh * 8 + i + shift) & 63;
        int cc = (ww * 8 + j + shift) & 63;
        const float* xrow = x + ((size_t)(b * 4096 + rr * 64 + cc)) * 256 + lg * 8;
        #pragma unroll
        for (int kt = 0; kt < 8; ++kt) {
            float4 v0 = *reinterpret_cast<const float4*>(xrow + kt * 32);
            float4 v1 = *reinterpret_cast<const float4*>(xrow + kt * 32 + 4);
            af[kt] = cvt8(v0, v1);
        }
    }

    // shift-mask regions: rows owned by this lane (C/D layout) and key cols
    int regr[4], regc[4];
    #pragma unroll
    for (int r = 0; r < 4; ++r) {
        int n = tokr0 + r;
        int pr = wh * 8 + (n >> 3), pc = ww * 8 + (n & 7);
        regr[r] = ((pr < 56) ? 0 : ((pr < 60) ? 1 : 2)) * 3 +
                  ((pc < 56) ? 0 : ((pc < 60) ? 1 : 2));
    }
    #pragma unroll
    for (int nf = 0; nf < 4; ++nf) {
        int kc = nf * 16 + lr;
        int pr = wh * 8 + (kc >> 3), pc = ww * 8 + (kc & 7);
        regc[nf] = ((pr < 56) ? 0 : ((pr < 60) ? 1 : 2)) * 3 +
                   ((pc < 56) ? 0 : ((pc < 60) ? 1 : 2));
    }

    for (int hp = 0; hp < 4; ++hp) {
        // ---- QKV GEMM for head pair: N = 192 (qA,kA,vA,qB,kB,vB), K=256 ----
        f32x4 acc[12];
        #pragma unroll
        for (int i = 0; i < 12; ++i) acc[i] = zf;
        int brow[12];
        #pragma unroll
        for (int p = 0; p < 2; ++p)
            #pragma unroll
            for (int mm = 0; mm < 3; ++mm)
                #pragma unroll
                for (int f = 0; f < 2; ++f)
                    brow[p * 6 + mm * 2 + f] = mm * 256 + (hp * 2 + p) * 32 + f * 16 + lr;

        for (int kt = 0; kt < 8; ++kt) {
            #pragma unroll
            for (int i = 0; i < 12; ++i) {
                bf16x8 bfr = *reinterpret_cast<const bf16x8*>(
                    qwb + (size_t)brow[i] * 256 + kt * 32 + lg * 8);
                acc[i] = MFMA16(af[kt], bfr, acc[i]);
            }
        }

        // ---- per head: bias + L2-norm q,k; write q,k (token-major), v (transposed) ----
        #pragma unroll
        for (int p = 0; p < 2; ++p) {
            const int h = hp * 2 + p;
            const float bq0 = qb[h * 32 + lr],       bq1 = qb[h * 32 + 16 + lr];
            const float bk0 = qb[256 + h * 32 + lr], bk1 = qb[256 + h * 32 + 16 + lr];
            const float bv0 = qb[512 + h * 32 + lr], bv1 = qb[512 + h * 32 + 16 + lr];
            f32x4 q0 = acc[p * 6 + 0], q1 = acc[p * 6 + 1];
            f32x4 k0 = acc[p * 6 + 2], k1 = acc[p * 6 + 3];
            f32x4 v0 = acc[p * 6 + 4], v1 = acc[p * 6 + 5];

            float qv0[4], qv1[4], kv0[4], kv1[4], sq[4], sk[4];
            #pragma unroll
            for (int r = 0; r < 4; ++r) {
                qv0[r] = q0[r] + bq0; qv1[r] = q1[r] + bq1;
                kv0[r] = k0[r] + bk0; kv1[r] = k1[r] + bk1;
                sq[r] = qv0[r] * qv0[r] + qv1[r] * qv1[r];
                sk[r] = kv0[r] * kv0[r] + kv1[r] * kv1[r];
            }
            #pragma unroll
            for (int m = 1; m < 16; m <<= 1)
                #pragma unroll
                for (int r = 0; r < 4; ++r) {
                    sq[r] += __shfl_xor(sq[r], m);
                    sk[r] += __shfl_xor(sk[r], m);
                }
            #pragma unroll
            for (int r = 0; r < 4; ++r) {
                float qi = 1.0f / (sqrtf(sq[r]) + 1e-12f);
                float ki = 1.0f / (sqrtf(sk[r]) + 1e-12f);
                int tok = tokr0 + r;
                qm[tok * 72 + p * 32 + lr]      = f2b(qv0[r] * qi);
                qm[tok * 72 + p * 32 + 16 + lr] = f2b(qv1[r] * qi);
                km[tok * 72 + p * 32 + lr]      = f2b(kv0[r] * ki);
                km[tok * 72 + p * 32 + 16 + lr] = f2b(kv1[r] * ki);
            }
            ushort4 u0 = { f2b(v0[0] + bv0), f2b(v0[1] + bv0), f2b(v0[2] + bv0), f2b(v0[3] + bv0) };
            ushort4 u1 = { f2b(v1[0] + bv1), f2b(v1[1] + bv1), f2b(v1[2] + bv1), f2b(v1[3] + bv1) };
            *reinterpret_cast<ushort4*>(vT + (p * 32 + lr) * 72      + wtile + lg * 4) = u0;
            *reinterpret_cast<ushort4*>(vT + (p * 32 + 16 + lr) * 72 + wtile + lg * 4) = u1;
        }
        __syncthreads();   // km / vT visible to all waves

        // ---- per head: S, softmax, PV, out ----
        #pragma unroll
        for (int p = 0; p < 2; ++p) {
            const int h = hp * 2 + p;
            f32x4 sacc[4];
            {
                bf16x8 aq = *reinterpret_cast<const bf16x8*>(qm + (wtile + lr) * 72 + p * 32 + lg * 8);
                #pragma unroll
                for (int nf = 0; nf < 4; ++nf) {
                    bf16x8 bk = *reinterpret_cast<const bf16x8*>(km + (nf * 16 + lr) * 72 + p * 32 + lg * 8);
                    sacc[nf] = MFMA16(aq, bk, zf);
                }
            }
            const float scale = __expf(fminf(lsc[h], 4.6051702f));
            const float* brow0 = biasx + ((size_t)(h * 64 + tokr0)) * 64;

            float mx[4] = { -1e30f, -1e30f, -1e30f, -1e30f };
            #pragma unroll
            for (int nf = 0; nf < 4; ++nf) {
                int kc = nf * 16 + lr;
                #pragma unroll
                for (int r = 0; r < 4; ++r) {
                    float v = sacc[nf][r] * scale + brow0[(size_t)r * 64 + kc];
                    if (shift && regc[nf] != regr[r]) v -= 100.0f;
                    sacc[nf][r] = v;
                    mx[r] = fmaxf(mx[r], v);
                }
            }
            #pragma unroll
            for (int m = 1; m < 16; m <<= 1)
                #pragma unroll
                for (int r = 0; r < 4; ++r) mx[r] = fmaxf(mx[r], __shfl_xor(mx[r], m));

            float sum[4] = { 0.f, 0.f, 0.f, 0.f };
            #pragma unroll
            for (int nf = 0; nf < 4; ++nf)
                #pragma unroll
                for (int r = 0; r < 4; ++r) {
                    float e = __expf(sacc[nf][r] - mx[r]);
                    sacc[nf][r] = e;
                    sum[r] += e;
                }
            #pragma unroll
            for (int m = 1; m < 16; m <<= 1)
                #pragma unroll
                for (int r = 0; r < 4; ++r) sum[r] += __shfl_xor(sum[r], m);

            // unnormalized P -> LDS (own-wave rows only)
            #pragma unroll
            for (int nf = 0; nf < 4; ++nf)
                #pragma unroll
                for (int r = 0; r < 4; ++r)
                    Pm[(tokr0 + r) * 72 + nf * 16 + lr] = f2b(sacc[nf][r]);

            // PV: M=16/wave, N=32, K=64
            f32x4 oacc[2] = { zf, zf };
            #pragma unroll
            for (int ks = 0; ks < 2; ++ks) {
                bf16x8 ap = *reinterpret_cast<const bf16x8*>(Pm + (wtile + lr) * 72 + ks * 32 + lg * 8);
                #pragma unroll
                for (int nf = 0; nf < 2; ++nf) {
                    bf16x8 bv = *reinterpret_cast<const bf16x8*>(vT + (p * 32 + nf * 16 + lr) * 72 + ks * 32 + lg * 8);
                    oacc[nf] = MFMA16(ap, bv, oacc[nf]);
                }
            }
            float inv[4];
            #pragma unroll
            for (int r = 0; r < 4; ++r) inv[r] = 1.0f / sum[r];
            #pragma unroll
            for (int nf = 0; nf < 2; ++nf)
                #pragma unroll
                for (int r = 0; r < 4; ++r)
                    ao[((size_t)(win * 64 + tokr0 + r)) * 256 + h * 32 + nf * 16 + lr] =
                        f2b(oacc[nf][r] * inv[r]);
        }
        __syncthreads();   // protect qm/km/vT before next pair
    }
}

// ---------------- proj (bf16 MFMA) + bias + post-LN + un-roll scatter + residual ----------------
// 16 tokens per block, 4 waves; wave w owns output cols [w*64, w*64+64)
__global__ __launch_bounds__(256, 4) void proj_mfma_kernel(
    const ushort* __restrict__ aob, const ushort* __restrict__ pwb,
    const float* __restrict__ pb, const float* __restrict__ n1s,
    const float* __restrict__ n1b, const float* __restrict__ xin,
    float* __restrict__ xout, int shift)
{
    extern __shared__ float outT[];   // [16][264]
    const int t = threadIdx.x;
    const size_t tok0 = (size_t)blockIdx.x * 16;
    const int w = t >> 6, l = t & 63, lr = l & 15, lg = l >> 4;
    const f32x4 zf = { 0.f, 0.f, 0.f, 0.f };

    // A straight from bf16 global
    bf16x8 af[8];
    #pragma unroll
    for (int kt = 0; kt < 8; ++kt)
        af[kt] = *reinterpret_cast<const bf16x8*>(aob + (tok0 + lr) * 256 + kt * 32 + lg * 8);

    f32x4 acc[4];
    #pragma unroll
    for (int nf = 0; nf < 4; ++nf) acc[nf] = zf;
    for (int kt = 0; kt < 8; ++kt) {
        #pragma unroll
        for (int nf = 0; nf < 4; ++nf) {
            bf16x8 bfr = *reinterpret_cast<const bf16x8*>(
                pwb + (size_t)(w * 64 + nf * 16 + lr) * 256 + kt * 32 + lg * 8);
            acc[nf] = MFMA16(af[kt], bfr, acc[nf]);
        }
    }
    #pragma unroll
    for (int nf = 0; nf < 4; ++nf) {
        int c = w * 64 + nf * 16 + lr;
        float bb = pb[c];
        #pragma unroll
        for (int r = 0; r < 4; ++r)
            outT[(lg * 4 + r) * 264 + c] = acc[nf][r] + bb;
    }
    __syncthreads();

    // LN + un-roll scatter + residual: wave w handles tokens w*4 .. w*4+3
    for (int u = 0; u < 4; ++u) {
        int tk = w * 4 + u;
        float v0 = outT[tk * 264 + l];
        float v1 = outT[tk * 264 + l + 64];
        float v2 = outT[tk * 264 + l + 128];
        float v3 = outT[tk * 264 + l + 192];
        float s = v0 + v1 + v2 + v3, ss = v0 * v0 + v1 * v1 + v2 * v2 + v3 * v3;
        for (int m = 1; m < 64; m <<= 1) { s += __shfl_xor(s, m); ss += __shfl_xor(ss, m); }
        float mean = s * (1.0f / 256.0f);
        float var  = ss * (1.0f / 256.0f) - mean * mean;
        float rs   = rsqrtf(var + 1e-5f);

        size_t gt = tok0 + tk;
        int win = (int)(gt >> 6), n = (int)(gt & 63);
        int b = win >> 6, wh = (win >> 3) & 7, ww = win & 7, i = n >> 3, j = n & 7;
        int pr = (wh * 8 + i + shift) & 63;
        int pc = (ww * 8 + j + shift) & 63;
        size_t gaddr = ((size_t)(b * 4096 + pr * 64 + pc)) * 256;
        xout[gaddr + l]       = xin[gaddr + l]       + (v0 - mean) * rs * n1s[l]       + n1b[l];
        xout[gaddr + l + 64]  = xin[gaddr + l + 64]  + (v1 - mean) * rs * n1s[l + 64]  + n1b[l + 64];
        xout[gaddr + l + 128] = xin[gaddr + l + 128] + (v2 - mean) * rs * n1s[l + 128] + n1b[l + 128];
        xout[gaddr + l + 192] = xin[gaddr + l + 192] + (v3 - mean) * rs * n1s[l + 192] + n1b[l + 192];
    }
}

// ---------------- fused MLP (bf16 MFMA): 256 -> 1024 gelu -> 256, post-LN, residual ----------------
// 32 tokens per block, 8 waves (512 thr); GEMM1: wave owns hid cols [wid*128,+128);
// GEMM2: wave owns out cols [wid*32,+32)
__global__ __launch_bounds__(512, 4) void mlp_mfma_kernel(
    float* __restrict__ x, const ushort* __restrict__ w1b, const float* __restrict__ b1,
    const ushort* __restrict__ w2b, const float* __restrict__ b2,
    const float* __restrict__ n2s, const float* __restrict__ n2b)
{
    extern __shared__ ushort hid[];        // [32][1032] bf16
    float* outT = (float*)hid;             // [32][264] f32 overlay (after GEMM2)

    const int t = threadIdx.x;
    const size_t tok0 = (size_t)blockIdx.x * 32;
    const int wid = t >> 6, l = t & 63, lr = l & 15, lg = l >> 4;
    const f32x4 zf = { 0.f, 0.f, 0.f, 0.f };

    // ---- GEMM1: hid[32][1024] = gelu(x @ w1^T + b1); wave cols n0..n0+127 ----
    {
        const int n0 = wid * 128;
        f32x4 acc[2][8];
        #pragma unroll
        for (int mf = 0; mf < 2; ++mf)
            #pragma unroll
            for (int nf = 0; nf < 8; ++nf) acc[mf][nf] = zf;

        const float* xr0 = x + (tok0 + lr) * 256 + lg * 8;
        const float* xr1 = x + (tok0 + 16 + lr) * 256 + lg * 8;
        for (int kt = 0; kt < 8; ++kt) {
            float4 p0 = *reinterpret_cast<const float4*>(xr0 + kt * 32);
            float4 p1 = *reinterpret_cast<const float4*>(xr0 + kt * 32 + 4);
            float4 p2 = *reinterpret_cast<const float4*>(xr1 + kt * 32);
            float4 p3 = *reinterpret_cast<const float4*>(xr1 + kt * 32 + 4);
            bf16x8 a0 = cvt8(p0, p1);
            bf16x8 a1 = cvt8(p2, p3);
            #pragma unroll
            for (int nf = 0; nf < 8; ++nf) {
                bf16x8 bfr = *reinterpret_cast<const bf16x8*>(
                    w1b + (size_t)(n0 + nf * 16 + lr) * 256 + kt * 32 + lg * 8);
                acc[0][nf] = MFMA16(a0, bfr, acc[0][nf]);
                acc[1][nf] = MFMA16(a1, bfr, acc[1][nf]);
            }
        }
        #pragma unroll
        for (int nf = 0; nf < 8; ++nf) {
            int hcol = n0 + nf * 16 + lr;
            float bb = b1[hcol];
            #pragma unroll
            for (int mf = 0; mf < 2; ++mf)
                #pragma unroll
                for (int r = 0; r < 4; ++r) {
                    int hrow = mf * 16 + lg * 4 + r;
                    float pre = acc[mf][nf][r] + bb;
                    float g = 0.5f * pre * (1.0f + erff(pre * 0.70710678f));  // exact gelu
                    hid[hrow * 1032 + hcol] = f2b(g);
                }
        }
    }
    __syncthreads();

    // ---- GEMM2: out[32][256] = hid @ w2^T; wave cols wid*32..+31 ----
    f32x4 acc2[2][2];
    #pragma unroll
    for (int mf = 0; mf < 2; ++mf)
        #pragma unroll
        for (int nf = 0; nf < 2; ++nf) acc2[mf][nf] = zf;
    {
        const int n2 = wid * 32;
        for (int kt = 0; kt < 32; ++kt) {
            bf16x8 a0 = *reinterpret_cast<const bf16x8*>(hid + lr * 1032        + kt * 32 + lg * 8);
            bf16x8 a1 = *reinterpret_cast<const bf16x8*>(hid + (16 + lr) * 1032 + kt * 32 + lg * 8);
            #pragma unroll
            for (int nf = 0; nf < 2; ++nf) {
                bf16x8 bfr = *reinterpret_cast<const bf16x8*>(
                    w2b + (size_t)(n2 + nf * 16 + lr) * 1024 + kt * 32 + lg * 8);
                acc2[0][nf] = MFMA16(a0, bfr, acc2[0][nf]);
                acc2[1][nf] = MFMA16(a1, bfr, acc2[1][nf]);
            }
        }
    }
    __syncthreads();   // all hid reads done before overlaying outT

    #pragma unroll
    for (int nf = 0; nf < 2; ++nf) {
        int c = wid * 32 + nf * 16 + lr;
        float bb = b2[c];
        #pragma unroll
        for (int mf = 0; mf < 2; ++mf)
            #pragma unroll
            for (int r = 0; r < 4; ++r)
                outT[(mf * 16 + lg * 4 + r) * 264 + c] = acc2[mf][nf][r] + bb;
    }
    __syncthreads();

    // ---- LN + residual: wave wid handles tokens wid*4 .. wid*4+3 ----
    for (int u = 0; u < 4; ++u) {
        int tk = wid * 4 + u;
        float v0 = outT[tk * 264 + l];
        float v1 = outT[tk * 264 + l + 64];
        float v2 = outT[tk * 264 + l + 128];
        float v3 = outT[tk * 264 + l + 192];
        float s = v0 + v1 + v2 + v3, ss = v0 * v0 + v1 * v1 + v2 * v2 + v3 * v3;
        for (int m = 1; m < 64; m <<= 1) { s += __shfl_xor(s, m); ss += __shfl_xor(ss, m); }
        float mean = s * (1.0f / 256.0f);
        float var  = ss * (1.0f / 256.0f) - mean * mean;
        float rs   = rsqrtf(var + 1e-5f);
        float* xp = x + (tok0 + tk) * 256;
        xp[l]       += (v0 - mean) * rs * n2s[l]       + n2b[l];
        xp[l + 64]  += (v1 - mean) * rs * n2s[l + 64]  + n2b[l + 64];
        xp[l + 128] += (v2 - mean) * rs * n2s[l + 128] + n2b[l + 128];
        xp[l + 192] += (v3 - mean) * rs * n2s[l + 192] + n2b[l + 192];
    }
}

// ---------------- launcher ----------------
extern "C" void kernel_launch(void* const* d_in, const int* in_sizes, int n_in,
                              void* d_out, int out_size, void* d_ws, size_t ws_size,
                              hipStream_t stream) {
    (void)in_sizes; (void)n_in; (void)out_size; (void)ws_size;
    const float* tokens = (const float*)d_in[0];
    const float* qkv_w  = (const float*)d_in[3];
    const float* qkv_b  = (const float*)d_in[4];
    const float* lsc    = (const float*)d_in[5];
    const float* cw1    = (const float*)d_in[6];
    const float* cb1    = (const float*)d_in[7];
    const float* cw2    = (const float*)d_in[8];
    const float* pw     = (const float*)d_in[9];
    const float* pb     = (const float*)d_in[10];
    const float* n1s    = (const float*)d_in[11];
    const float* n1b    = (const float*)d_in[12];
    const float* mw1    = (const float*)d_in[13];
    const float* mb1    = (const float*)d_in[14];
    const float* mw2    = (const float*)d_in[15];
    const float* mb2    = (const float*)d_in[16];
    const float* n2s    = (const float*)d_in[17];
    const float* n2b    = (const float*)d_in[18];

    float* x = (float*)d_out;

    // workspace layout (all 16B aligned)
    ushort* attn_out = (ushort*)d_ws;                                  // 32 MB
    float*  biastab  = (float*)((char*)d_ws + (size_t)NTOK * C_ * 2);  // 7200 B
    ushort* pwb      = (ushort*)((char*)biastab + 7200);               // 256 KB
    ushort* w1b      = pwb + 2 * 256 * 256;                            // 1 MB
    ushort* w2b      = w1b + 2 * 1024 * 256;                           // 1 MB
    ushort* qwb      = w2b + 2 * 256 * 1024;                           // 768 KB
    float*  biasx    = (float*)(qwb + 2 * 768 * 256);                  // 128 KB

    f2b_kernel<<<dim3(2 * 256 * 256 / 1024),  dim3(256), 0, stream>>>(pwb, pw);
    f2b_kernel<<<dim3(2 * 1024 * 256 / 1024), dim3(256), 0, stream>>>(w1b, mw1);
    f2b_kernel<<<dim3(2 * 256 * 1024 / 1024), dim3(256), 0, stream>>>(w2b, mw2);
    f2b_kernel<<<dim3(2 * 768 * 256 / 1024),  dim3(256), 0, stream>>>(qwb, qkv_w);

    for (int l = 0; l < 2; ++l) {
        const int shift = l ? 4 : 0;
        const float* xsrc = (l == 0) ? tokens : x;   // attn + proj-residual source
        cpb_kernel<<<dim3(225), dim3(256), 0, stream>>>(
            cw1 + (size_t)l * 1024, cb1 + (size_t)l * 512, cw2 + (size_t)l * 4096, biastab);
        biasx_kernel<<<dim3(512), dim3(64), 0, stream>>>(biastab, biasx);
        attn_mfma_kernel<<<dim3(1024), dim3(256), ATTN_LDS, stream>>>(
            xsrc, qwb + (size_t)l * 196608, qkv_b + (size_t)l * 768,
            lsc + (size_t)l * 8, biasx, attn_out, shift);
        proj_mfma_kernel<<<dim3(NTOK / 16), dim3(256), PROJ_LDS, stream>>>(
            attn_out, pwb + (size_t)l * 65536, pb + (size_t)l * 256,
            n1s + (size_t)l * 256, n1b + (size_t)l * 256, xsrc, x, shift);
        mlp_mfma_kernel<<<dim3(NTOK / 32), dim3(512), MLP_LDS, stream>>>(
            x, w1b + (size_t)l * 262144, mb1 + (size_t)l * 1024,
            w2b + (size_t)l * 262144, mb2 + (size_t)l * 256,
            n2s + (size_t)l * 256, n2b + (size_t)l * 256);
    }
}

// Round 5
// 986.879 us; speedup vs baseline: 1.2845x; 1.2845x over previous
//
#include <hip/hip_runtime.h>
#include <math.h>

// ---------------- problem constants ----------------
#define C_    256
#define NTOK  65536   // B * 64 * 64

// LDS sizes (bytes)
#define ATTN_LDS (64*72*2*4)   // qm,km,vT,Pm : 36,864
#define PROJ_LDS (64*264*4)    // outT        : 67,584
#define MLP_LDS  (64*264*4)    // max(xs+hc = 65,536, outT = 67,584)

typedef __bf16 bf16x8 __attribute__((ext_vector_type(8)));
typedef float  f32x4  __attribute__((ext_vector_type(4)));
#define MFMA16(a,b,c) __builtin_amdgcn_mfma_f32_16x16x32_bf16((a),(b),(c),0,0,0)

__device__ inline ushort f2b(float f) {
    unsigned u = __builtin_bit_cast(unsigned, f);
    return (ushort)((u + 0x7fffu + ((u >> 16) & 1u)) >> 16);   // RNE
}

union BF8u { ushort u[8]; bf16x8 v; };
__device__ inline bf16x8 cvt8(float4 a, float4 b) {
    BF8u t;
    t.u[0] = f2b(a.x); t.u[1] = f2b(a.y); t.u[2] = f2b(a.z); t.u[3] = f2b(a.w);
    t.u[4] = f2b(b.x); t.u[5] = f2b(b.y); t.u[6] = f2b(b.z); t.u[7] = f2b(b.w);
    return t.v;
}

// ---------------- f32 -> bf16 weight conversion ----------------
__global__ void f2b_kernel(ushort* __restrict__ dst, const float* __restrict__ src) {
    size_t i = ((size_t)blockIdx.x * 256 + threadIdx.x) * 4;
    float4 v = *reinterpret_cast<const float4*>(src + i);
    ushort4 u = { f2b(v.x), f2b(v.y), f2b(v.z), f2b(v.w) };
    *reinterpret_cast<ushort4*>(dst + i) = u;
}

// ---------------- continuous position bias table ----------------
__global__ void cpb_kernel(const float* __restrict__ w1, const float* __restrict__ b1,
                           const float* __restrict__ w2, float* __restrict__ biastab) {
    __shared__ float red[256];
    const int e = blockIdx.x;
    const int t = threadIdx.x;
    const int p = e / 15, q = e % 15;
    const float v0 = (float)(p - 7) * (8.0f / 7.0f);
    const float v1 = (float)(q - 7) * (8.0f / 7.0f);
    const float t0 = copysignf(log2f(fabsf(v0) + 1.0f) * (1.0f / 3.0f), v0);
    const float t1 = copysignf(log2f(fabsf(v1) + 1.0f) * (1.0f / 3.0f), v1);
    const float ha = fmaxf(0.0f, t0 * w1[t * 2]         + t1 * w1[t * 2 + 1]         + b1[t]);
    const float hb = fmaxf(0.0f, t0 * w1[(t + 256) * 2] + t1 * w1[(t + 256) * 2 + 1] + b1[t + 256]);
    for (int h = 0; h < 8; ++h) {
        __syncthreads();
        red[t] = ha * w2[h * 512 + t] + hb * w2[h * 512 + t + 256];
        __syncthreads();
        for (int s = 128; s > 0; s >>= 1) {
            if (t < s) red[t] += red[t + s];
            __syncthreads();
        }
        if (t == 0) biastab[e * 8 + h] = 16.0f / (1.0f + expf(-red[0]));
    }
}

// ---------------- expand bias to [8][64][64] ----------------
__global__ void biasx_kernel(const float* __restrict__ biastab, float* __restrict__ biasx) {
    int h = blockIdx.x >> 6, n = blockIdx.x & 63, m = threadIdx.x;
    int idx = ((n >> 3) - (m >> 3) + 7) * 15 + ((n & 7) - (m & 7) + 7);
    biasx[((size_t)(h * 64 + n)) * 64 + m] = biastab[idx * 8 + h];
}

// ---------------- fused window attention (bf16 MFMA, head pairs) ----------------
// one block per window, 4 waves; wave w owns token rows [w*16, w*16+16)
__global__ __launch_bounds__(256, 4) void attn_mfma_kernel(
    const float* __restrict__ x, const ushort* __restrict__ qwb,
    const float* __restrict__ qb, const float* __restrict__ lsc,
    const float* __restrict__ biasx, ushort* __restrict__ ao, int shift)
{
    extern __shared__ ushort sm[];
    ushort* qm = sm;              // [64][72]
    ushort* km = sm + 64 * 72;    // [64][72]
    ushort* vT = km + 64 * 72;    // [64][72]
    ushort* Pm = vT + 64 * 72;    // [64][72]

    const int t   = threadIdx.x;
    const int win = blockIdx.x;
    const int b = win >> 6, wh = (win >> 3) & 7, ww = win & 7;
    const int w = t >> 6, l = t & 63, lr = l & 15, lg = l >> 4;
    const int wtile = w * 16;
    const int tokr0 = wtile + lg * 4;
    const f32x4 zf = { 0.f, 0.f, 0.f, 0.f };

    bf16x8 af[8];
    {
        int n = wtile + lr, i = n >> 3, j = n & 7;
        int rr = (wh * 8 + i + shift) & 63;
        int cc = (ww * 8 + j + shift) & 63;
        const float* xrow = x + ((size_t)(b * 4096 + rr * 64 + cc)) * 256 + lg * 8;
        #pragma unroll
        for (int kt = 0; kt < 8; ++kt) {
            float4 v0 = *reinterpret_cast<const float4*>(xrow + kt * 32);
            float4 v1 = *reinterpret_cast<const float4*>(xrow + kt * 32 + 4);
            af[kt] = cvt8(v0, v1);
        }
    }

    int regr[4], regc[4];
    #pragma unroll
    for (int r = 0; r < 4; ++r) {
        int n = tokr0 + r;
        int pr = wh * 8 + (n >> 3), pc = ww * 8 + (n & 7);
        regr[r] = ((pr < 56) ? 0 : ((pr < 60) ? 1 : 2)) * 3 +
                  ((pc < 56) ? 0 : ((pc < 60) ? 1 : 2));
    }
    #pragma unroll
    for (int nf = 0; nf < 4; ++nf) {
        int kc = nf * 16 + lr;
        int pr = wh * 8 + (kc >> 3), pc = ww * 8 + (kc & 7);
        regc[nf] = ((pr < 56) ? 0 : ((pr < 60) ? 1 : 2)) * 3 +
                   ((pc < 56) ? 0 : ((pc < 60) ? 1 : 2));
    }

    for (int hp = 0; hp < 4; ++hp) {
        f32x4 acc[12];
        #pragma unroll
        for (int i = 0; i < 12; ++i) acc[i] = zf;
        int brow[12];
        #pragma unroll
        for (int p = 0; p < 2; ++p)
            #pragma unroll
            for (int mm = 0; mm < 3; ++mm)
                #pragma unroll
                for (int f = 0; f < 2; ++f)
                    brow[p * 6 + mm * 2 + f] = mm * 256 + (hp * 2 + p) * 32 + f * 16 + lr;

        for (int kt = 0; kt < 8; ++kt) {
            #pragma unroll
            for (int i = 0; i < 12; ++i) {
                bf16x8 bfr = *reinterpret_cast<const bf16x8*>(
                    qwb + (size_t)brow[i] * 256 + kt * 32 + lg * 8);
                acc[i] = MFMA16(af[kt], bfr, acc[i]);
            }
        }

        #pragma unroll
        for (int p = 0; p < 2; ++p) {
            const int h = hp * 2 + p;
            const float bq0 = qb[h * 32 + lr],       bq1 = qb[h * 32 + 16 + lr];
            const float bk0 = qb[256 + h * 32 + lr], bk1 = qb[256 + h * 32 + 16 + lr];
            const float bv0 = qb[512 + h * 32 + lr], bv1 = qb[512 + h * 32 + 16 + lr];
            f32x4 q0 = acc[p * 6 + 0], q1 = acc[p * 6 + 1];
            f32x4 k0 = acc[p * 6 + 2], k1 = acc[p * 6 + 3];
            f32x4 v0 = acc[p * 6 + 4], v1 = acc[p * 6 + 5];

            float qv0[4], qv1[4], kv0[4], kv1[4], sq[4], sk[4];
            #pragma unroll
            for (int r = 0; r < 4; ++r) {
                qv0[r] = q0[r] + bq0; qv1[r] = q1[r] + bq1;
                kv0[r] = k0[r] + bk0; kv1[r] = k1[r] + bk1;
                sq[r] = qv0[r] * qv0[r] + qv1[r] * qv1[r];
                sk[r] = kv0[r] * kv0[r] + kv1[r] * kv1[r];
            }
            #pragma unroll
            for (int m = 1; m < 16; m <<= 1)
                #pragma unroll
                for (int r = 0; r < 4; ++r) {
                    sq[r] += __shfl_xor(sq[r], m);
                    sk[r] += __shfl_xor(sk[r], m);
                }
            #pragma unroll
            for (int r = 0; r < 4; ++r) {
                float qi = 1.0f / (sqrtf(sq[r]) + 1e-12f);
                float ki = 1.0f / (sqrtf(sk[r]) + 1e-12f);
                int tok = tokr0 + r;
                qm[tok * 72 + p * 32 + lr]      = f2b(qv0[r] * qi);
                qm[tok * 72 + p * 32 + 16 + lr] = f2b(qv1[r] * qi);
                km[tok * 72 + p * 32 + lr]      = f2b(kv0[r] * ki);
                km[tok * 72 + p * 32 + 16 + lr] = f2b(kv1[r] * ki);
            }
            ushort4 u0 = { f2b(v0[0] + bv0), f2b(v0[1] + bv0), f2b(v0[2] + bv0), f2b(v0[3] + bv0) };
            ushort4 u1 = { f2b(v1[0] + bv1), f2b(v1[1] + bv1), f2b(v1[2] + bv1), f2b(v1[3] + bv1) };
            *reinterpret_cast<ushort4*>(vT + (p * 32 + lr) * 72      + wtile + lg * 4) = u0;
            *reinterpret_cast<ushort4*>(vT + (p * 32 + 16 + lr) * 72 + wtile + lg * 4) = u1;
        }
        __syncthreads();

        #pragma unroll
        for (int p = 0; p < 2; ++p) {
            const int h = hp * 2 + p;
            f32x4 sacc[4];
            {
                bf16x8 aq = *reinterpret_cast<const bf16x8*>(qm + (wtile + lr) * 72 + p * 32 + lg * 8);
                #pragma unroll
                for (int nf = 0; nf < 4; ++nf) {
                    bf16x8 bk = *reinterpret_cast<const bf16x8*>(km + (nf * 16 + lr) * 72 + p * 32 + lg * 8);
                    sacc[nf] = MFMA16(aq, bk, zf);
                }
            }
            const float scale = __expf(fminf(lsc[h], 4.6051702f));
            const float* brow0 = biasx + ((size_t)(h * 64 + tokr0)) * 64;

            float mx[4] = { -1e30f, -1e30f, -1e30f, -1e30f };
            #pragma unroll
            for (int nf = 0; nf < 4; ++nf) {
                int kc = nf * 16 + lr;
                #pragma unroll
                for (int r = 0; r < 4; ++r) {
                    float v = sacc[nf][r] * scale + brow0[(size_t)r * 64 + kc];
                    if (shift && regc[nf] != regr[r]) v -= 100.0f;
                    sacc[nf][r] = v;
                    mx[r] = fmaxf(mx[r], v);
                }
            }
            #pragma unroll
            for (int m = 1; m < 16; m <<= 1)
                #pragma unroll
                for (int r = 0; r < 4; ++r) mx[r] = fmaxf(mx[r], __shfl_xor(mx[r], m));

            float sum[4] = { 0.f, 0.f, 0.f, 0.f };
            #pragma unroll
            for (int nf = 0; nf < 4; ++nf)
                #pragma unroll
                for (int r = 0; r < 4; ++r) {
                    float e = __expf(sacc[nf][r] - mx[r]);
                    sacc[nf][r] = e;
                    sum[r] += e;
                }
            #pragma unroll
            for (int m = 1; m < 16; m <<= 1)
                #pragma unroll
                for (int r = 0; r < 4; ++r) sum[r] += __shfl_xor(sum[r], m);

            #pragma unroll
            for (int nf = 0; nf < 4; ++nf)
                #pragma unroll
                for (int r = 0; r < 4; ++r)
                    Pm[(tokr0 + r) * 72 + nf * 16 + lr] = f2b(sacc[nf][r]);

            f32x4 oacc[2] = { zf, zf };
            #pragma unroll
            for (int ks = 0; ks < 2; ++ks) {
                bf16x8 ap = *reinterpret_cast<const bf16x8*>(Pm + (wtile + lr) * 72 + ks * 32 + lg * 8);
                #pragma unroll
                for (int nf = 0; nf < 2; ++nf) {
                    bf16x8 bv = *reinterpret_cast<const bf16x8*>(vT + (p * 32 + nf * 16 + lr) * 72 + ks * 32 + lg * 8);
                    oacc[nf] = MFMA16(ap, bv, oacc[nf]);
                }
            }
            float inv[4];
            #pragma unroll
            for (int r = 0; r < 4; ++r) inv[r] = 1.0f / sum[r];
            #pragma unroll
            for (int nf = 0; nf < 2; ++nf)
                #pragma unroll
                for (int r = 0; r < 4; ++r)
                    ao[((size_t)(win * 64 + tokr0 + r)) * 256 + h * 32 + nf * 16 + lr] =
                        f2b(oacc[nf][r] * inv[r]);
        }
        __syncthreads();
    }
}

// ---------------- proj (bf16 MFMA, M=64/block) + bias + post-LN + scatter residual ----------------
// 64 tokens per block, 4 waves; wave w owns output cols [w*64, w*64+64)
__global__ __launch_bounds__(256, 2) void proj_mfma_kernel(
    const ushort* __restrict__ aob, const ushort* __restrict__ pwb,
    const float* __restrict__ pb, const float* __restrict__ n1s,
    const float* __restrict__ n1b, const float* __restrict__ xin,
    float* __restrict__ xout, int shift)
{
    extern __shared__ float outT[];   // [64][264]
    const int t = threadIdx.x;
    const size_t tok0 = (size_t)blockIdx.x * 64;
    const int w = t >> 6, l = t & 63, lr = l & 15, lg = l >> 4;
    const f32x4 zf = { 0.f, 0.f, 0.f, 0.f };

    f32x4 acc[4][4];   // [mf][nf]
    #pragma unroll
    for (int mf = 0; mf < 4; ++mf)
        #pragma unroll
        for (int nf = 0; nf < 4; ++nf) acc[mf][nf] = zf;

    for (int kt = 0; kt < 8; ++kt) {
        bf16x8 a[4], bfr[4];
        #pragma unroll
        for (int mf = 0; mf < 4; ++mf)
            a[mf] = *reinterpret_cast<const bf16x8*>(
                aob + (tok0 + mf * 16 + lr) * 256 + kt * 32 + lg * 8);
        #pragma unroll
        for (int nf = 0; nf < 4; ++nf)
            bfr[nf] = *reinterpret_cast<const bf16x8*>(
                pwb + (size_t)(w * 64 + nf * 16 + lr) * 256 + kt * 32 + lg * 8);
        #pragma unroll
        for (int mf = 0; mf < 4; ++mf)
            #pragma unroll
            for (int nf = 0; nf < 4; ++nf)
                acc[mf][nf] = MFMA16(a[mf], bfr[nf], acc[mf][nf]);
    }

    #pragma unroll
    for (int nf = 0; nf < 4; ++nf) {
        int c = w * 64 + nf * 16 + lr;
        float bb = pb[c];
        #pragma unroll
        for (int mf = 0; mf < 4; ++mf)
            #pragma unroll
            for (int r = 0; r < 4; ++r)
                outT[(mf * 16 + lg * 4 + r) * 264 + c] = acc[mf][nf][r] + bb;
    }
    __syncthreads();

    // LN + un-roll scatter + residual: wave w handles tokens w*16 .. w*16+15
    for (int u = 0; u < 16; ++u) {
        int tk = w * 16 + u;
        float v0 = outT[tk * 264 + l];
        float v1 = outT[tk * 264 + l + 64];
        float v2 = outT[tk * 264 + l + 128];
        float v3 = outT[tk * 264 + l + 192];
        float s = v0 + v1 + v2 + v3, ss = v0 * v0 + v1 * v1 + v2 * v2 + v3 * v3;
        for (int m = 1; m < 64; m <<= 1) { s += __shfl_xor(s, m); ss += __shfl_xor(ss, m); }
        float mean = s * (1.0f / 256.0f);
        float var  = ss * (1.0f / 256.0f) - mean * mean;
        float rs   = rsqrtf(var + 1e-5f);

        size_t gt = tok0 + tk;
        int win = (int)(gt >> 6), n = (int)(gt & 63);
        int b = win >> 6, wh = (win >> 3) & 7, ww = win & 7, i = n >> 3, j = n & 7;
        int pr = (wh * 8 + i + shift) & 63;
        int pc = (ww * 8 + j + shift) & 63;
        size_t gaddr = ((size_t)(b * 4096 + pr * 64 + pc)) * 256;
        xout[gaddr + l]       = xin[gaddr + l]       + (v0 - mean) * rs * n1s[l]       + n1b[l];
        xout[gaddr + l + 64]  = xin[gaddr + l + 64]  + (v1 - mean) * rs * n1s[l + 64]  + n1b[l + 64];
        xout[gaddr + l + 128] = xin[gaddr + l + 128] + (v2 - mean) * rs * n1s[l + 128] + n1b[l + 128];
        xout[gaddr + l + 192] = xin[gaddr + l + 192] + (v3 - mean) * rs * n1s[l + 192] + n1b[l + 192];
    }
}

// ---------------- fused MLP (bf16 MFMA, M=64/block, hid in 4 LDS chunks) ----------------
// 64 tokens per block, 4 waves. Per chunk c (256 hid cols):
//   GEMM1: wave w computes hid cols [c*256 + w*64, +64) -> gelu -> LDS chunk
//   GEMM2: wave w accumulates out cols [w*64, +64) over the chunk's K=256
__global__ __launch_bounds__(256, 2) void mlp_mfma_kernel(
    float* __restrict__ x, const ushort* __restrict__ w1b, const float* __restrict__ b1,
    const ushort* __restrict__ w2b, const float* __restrict__ b2,
    const float* __restrict__ n2s, const float* __restrict__ n2b)
{
    extern __shared__ ushort sm2[];
    ushort* xs = sm2;               // [64][256] bf16, swizzled
    ushort* hc = sm2 + 64 * 256;    // [64][256] bf16, swizzled (current chunk)
    float*  outT = (float*)sm2;     // [64][264] f32 overlay (epilogue)

    const int t = threadIdx.x;
    const size_t tok0 = (size_t)blockIdx.x * 64;
    const int w = t >> 6, l = t & 63, lr = l & 15, lg = l >> 4;
    const int aswz = (lr & 7) << 3;
    const f32x4 zf = { 0.f, 0.f, 0.f, 0.f };

    {   // stage x tile (f32 -> bf16, swizzled): thread covers row t>>2, cols (t&3)*64..+63
        int row = t >> 2, seg = t & 3;
        const float* src = x + (tok0 + row) * 256 + seg * 64;
        #pragma unroll
        for (int k8 = 0; k8 < 8; ++k8) {
            float4 v0 = *reinterpret_cast<const float4*>(src + k8 * 8);
            float4 v1 = *reinterpret_cast<const float4*>(src + k8 * 8 + 4);
            int col = seg * 64 + k8 * 8;
            *reinterpret_cast<bf16x8*>(xs + row * 256 + (col ^ ((row & 7) << 3))) = cvt8(v0, v1);
        }
    }
    __syncthreads();

    f32x4 acc2[4][4];   // persistent GEMM2 accumulator [mf][nf]
    #pragma unroll
    for (int mf = 0; mf < 4; ++mf)
        #pragma unroll
        for (int nf = 0; nf < 4; ++nf) acc2[mf][nf] = zf;

    for (int c = 0; c < 4; ++c) {
        // ---- GEMM1 chunk: M=64, N=64 (wave slice), K=256 ----
        f32x4 acc1[4][4];
        #pragma unroll
        for (int mf = 0; mf < 4; ++mf)
            #pragma unroll
            for (int nf = 0; nf < 4; ++nf) acc1[mf][nf] = zf;

        const int hcol0 = c * 256 + w * 64;
        for (int kt = 0; kt < 8; ++kt) {
            int k0 = kt * 32 + lg * 8;
            bf16x8 a[4], bfr[4];
            #pragma unroll
            for (int mf = 0; mf < 4; ++mf)
                a[mf] = *reinterpret_cast<const bf16x8*>(xs + (mf * 16 + lr) * 256 + (k0 ^ aswz));
            #pragma unroll
            for (int nf = 0; nf < 4; ++nf)
                bfr[nf] = *reinterpret_cast<const bf16x8*>(
                    w1b + (size_t)(hcol0 + nf * 16 + lr) * 256 + k0);
            #pragma unroll
            for (int mf = 0; mf < 4; ++mf)
                #pragma unroll
                for (int nf = 0; nf < 4; ++nf)
                    acc1[mf][nf] = MFMA16(a[mf], bfr[nf], acc1[mf][nf]);
        }

        __syncthreads();   // previous chunk's GEMM2 reads of hc are done

        // ---- gelu -> hc (swizzled bf16; local cols w*64 + nf*16 + lr) ----
        #pragma unroll
        for (int nf = 0; nf < 4; ++nf) {
            int lcol = w * 64 + nf * 16 + lr;
            float bb = b1[c * 256 + lcol];
            #pragma unroll
            for (int mf = 0; mf < 4; ++mf)
                #pragma unroll
                for (int r = 0; r < 4; ++r) {
                    int hrow = mf * 16 + lg * 4 + r;
                    float pre = acc1[mf][nf][r] + bb;
                    float g = 0.5f * pre * (1.0f + erff(pre * 0.70710678f));
                    hc[hrow * 256 + (lcol ^ ((hrow & 7) << 3))] = f2b(g);
                }
        }
        __syncthreads();

        // ---- GEMM2 partial: M=64, N=64 (wave slice), K=256 (this chunk) ----
        for (int kt = 0; kt < 8; ++kt) {
            int k0 = kt * 32 + lg * 8;
            bf16x8 a[4], bfr[4];
            #pragma unroll
            for (int mf = 0; mf < 4; ++mf)
                a[mf] = *reinterpret_cast<const bf16x8*>(hc + (mf * 16 + lr) * 256 + (k0 ^ aswz));
            #pragma unroll
            for (int nf = 0; nf < 4; ++nf)
                bfr[nf] = *reinterpret_cast<const bf16x8*>(
                    w2b + (size_t)(w * 64 + nf * 16 + lr) * 1024 + c * 256 + k0);
            #pragma unroll
            for (int mf = 0; mf < 4; ++mf)
                #pragma unroll
                for (int nf = 0; nf < 4; ++nf)
                    acc2[mf][nf] = MFMA16(a[mf], bfr[nf], acc2[mf][nf]);
        }
    }
    __syncthreads();   // last chunk's hc reads done; overlay outT

    #pragma unroll
    for (int nf = 0; nf < 4; ++nf) {
        int cc = w * 64 + nf * 16 + lr;
        float bb = b2[cc];
        #pragma unroll
        for (int mf = 0; mf < 4; ++mf)
            #pragma unroll
            for (int r = 0; r < 4; ++r)
                outT[(mf * 16 + lg * 4 + r) * 264 + cc] = acc2[mf][nf][r] + bb;
    }
    __syncthreads();

    // ---- LN + residual: wave w handles tokens w*16 .. w*16+15 ----
    for (int u = 0; u < 16; ++u) {
        int tk = w * 16 + u;
        float v0 = outT[tk * 264 + l];
        float v1 = outT[tk * 264 + l + 64];
        float v2 = outT[tk * 264 + l + 128];
        float v3 = outT[tk * 264 + l + 192];
        float s = v0 + v1 + v2 + v3, ss = v0 * v0 + v1 * v1 + v2 * v2 + v3 * v3;
        for (int m = 1; m < 64; m <<= 1) { s += __shfl_xor(s, m); ss += __shfl_xor(ss, m); }
        float mean = s * (1.0f / 256.0f);
        float var  = ss * (1.0f / 256.0f) - mean * mean;
        float rs   = rsqrtf(var + 1e-5f);
        float* xp = x + (tok0 + tk) * 256;
        xp[l]       += (v0 - mean) * rs * n2s[l]       + n2b[l];
        xp[l + 64]  += (v1 - mean) * rs * n2s[l + 64]  + n2b[l + 64];
        xp[l + 128] += (v2 - mean) * rs * n2s[l + 128] + n2b[l + 128];
        xp[l + 192] += (v3 - mean) * rs * n2s[l + 192] + n2b[l + 192];
    }
}

// ---------------- launcher ----------------
extern "C" void kernel_launch(void* const* d_in, const int* in_sizes, int n_in,
                              void* d_out, int out_size, void* d_ws, size_t ws_size,
                              hipStream_t stream) {
    (void)in_sizes; (void)n_in; (void)out_size; (void)ws_size;
    const float* tokens = (const float*)d_in[0];
    const float* qkv_w  = (const float*)d_in[3];
    const float* qkv_b  = (const float*)d_in[4];
    const float* lsc    = (const float*)d_in[5];
    const float* cw1    = (const float*)d_in[6];
    const float* cb1    = (const float*)d_in[7];
    const float* cw2    = (const float*)d_in[8];
    const float* pw     = (const float*)d_in[9];
    const float* pb     = (const float*)d_in[10];
    const float* n1s    = (const float*)d_in[11];
    const float* n1b    = (const float*)d_in[12];
    const float* mw1    = (const float*)d_in[13];
    const float* mb1    = (const float*)d_in[14];
    const float* mw2    = (const float*)d_in[15];
    const float* mb2    = (const float*)d_in[16];
    const float* n2s    = (const float*)d_in[17];
    const float* n2b    = (const float*)d_in[18];

    float* x = (float*)d_out;

    // workspace layout (all 16B aligned)
    ushort* attn_out = (ushort*)d_ws;                                  // 32 MB
    float*  biastab  = (float*)((char*)d_ws + (size_t)NTOK * C_ * 2);  // 7200 B
    ushort* pwb      = (ushort*)((char*)biastab + 7200);               // 256 KB
    ushort* w1b      = pwb + 2 * 256 * 256;                            // 1 MB
    ushort* w2b      = w1b + 2 * 1024 * 256;                           // 1 MB
    ushort* qwb      = w2b + 2 * 256 * 1024;                           // 768 KB
    float*  biasx    = (float*)(qwb + 2 * 768 * 256);                  // 128 KB

    f2b_kernel<<<dim3(2 * 256 * 256 / 1024),  dim3(256), 0, stream>>>(pwb, pw);
    f2b_kernel<<<dim3(2 * 1024 * 256 / 1024), dim3(256), 0, stream>>>(w1b, mw1);
    f2b_kernel<<<dim3(2 * 256 * 1024 / 1024), dim3(256), 0, stream>>>(w2b, mw2);
    f2b_kernel<<<dim3(2 * 768 * 256 / 1024),  dim3(256), 0, stream>>>(qwb, qkv_w);

    for (int l = 0; l < 2; ++l) {
        const int shift = l ? 4 : 0;
        const float* xsrc = (l == 0) ? tokens : x;
        cpb_kernel<<<dim3(225), dim3(256), 0, stream>>>(
            cw1 + (size_t)l * 1024, cb1 + (size_t)l * 512, cw2 + (size_t)l * 4096, biastab);
        biasx_kernel<<<dim3(512), dim3(64), 0, stream>>>(biastab, biasx);
        attn_mfma_kernel<<<dim3(1024), dim3(256), ATTN_LDS, stream>>>(
            xsrc, qwb + (size_t)l * 196608, qkv_b + (size_t)l * 768,
            lsc + (size_t)l * 8, biasx, attn_out, shift);
        proj_mfma_kernel<<<dim3(NTOK / 64), dim3(256), PROJ_LDS, stream>>>(
            attn_out, pwb + (size_t)l * 65536, pb + (size_t)l * 256,
            n1s + (size_t)l * 256, n1b + (size_t)l * 256, xsrc, x, shift);
        mlp_mfma_kernel<<<dim3(NTOK / 64), dim3(256), MLP_LDS, stream>>>(
            x, w1b + (size_t)l * 262144, mb1 + (size_t)l * 1024,
            w2b + (size_t)l * 262144, mb2 + (size_t)l * 256,
            n2s + (size_t)l * 256, n2b + (size_t)l * 256);
    }
}

// Round 6
// 877.183 us; speedup vs baseline: 1.4451x; 1.1251x over previous
//
#include <hip/hip_runtime.h>
#include <math.h>

// ---------------- problem constants ----------------
#define C_    256
#define NTOK  65536   // B * 64 * 64
#define HWIN  512     // windows per half

// LDS sizes (bytes)
#define AP_LDS  (4*64*72*2 + 64*256*2)   // P[4][64][72] + ao[64][256] = 69,632 (outT overlays)
#define MLP_LDS (64*264*4)               // 67,584

typedef __bf16 bf16x8 __attribute__((ext_vector_type(8)));
typedef float  f32x4  __attribute__((ext_vector_type(4)));
#define MFMA16(a,b,c) __builtin_amdgcn_mfma_f32_16x16x32_bf16((a),(b),(c),0,0,0)

__device__ inline ushort f2b(float f) {
    unsigned u = __builtin_bit_cast(unsigned, f);
    return (ushort)((u + 0x7fffu + ((u >> 16) & 1u)) >> 16);   // RNE
}

union BF8u { ushort u[8]; bf16x8 v; };
__device__ inline bf16x8 cvt8(float4 a, float4 b) {
    BF8u t;
    t.u[0] = f2b(a.x); t.u[1] = f2b(a.y); t.u[2] = f2b(a.z); t.u[3] = f2b(a.w);
    t.u[4] = f2b(b.x); t.u[5] = f2b(b.y); t.u[6] = f2b(b.z); t.u[7] = f2b(b.w);
    return t.v;
}

// ---------------- f32 -> bf16 weight conversion ----------------
__global__ void f2b_kernel(ushort* __restrict__ dst, const float* __restrict__ src) {
    size_t i = ((size_t)blockIdx.x * 256 + threadIdx.x) * 4;
    float4 v = *reinterpret_cast<const float4*>(src + i);
    ushort4 u = { f2b(v.x), f2b(v.y), f2b(v.z), f2b(v.w) };
    *reinterpret_cast<ushort4*>(dst + i) = u;
}

// ---------------- continuous position bias table ----------------
__global__ void cpb_kernel(const float* __restrict__ w1, const float* __restrict__ b1,
                           const float* __restrict__ w2, float* __restrict__ biastab) {
    __shared__ float red[256];
    const int e = blockIdx.x;
    const int t = threadIdx.x;
    const int p = e / 15, q = e % 15;
    const float v0 = (float)(p - 7) * (8.0f / 7.0f);
    const float v1 = (float)(q - 7) * (8.0f / 7.0f);
    const float t0 = copysignf(log2f(fabsf(v0) + 1.0f) * (1.0f / 3.0f), v0);
    const float t1 = copysignf(log2f(fabsf(v1) + 1.0f) * (1.0f / 3.0f), v1);
    const float ha = fmaxf(0.0f, t0 * w1[t * 2]         + t1 * w1[t * 2 + 1]         + b1[t]);
    const float hb = fmaxf(0.0f, t0 * w1[(t + 256) * 2] + t1 * w1[(t + 256) * 2 + 1] + b1[t + 256]);
    for (int h = 0; h < 8; ++h) {
        __syncthreads();
        red[t] = ha * w2[h * 512 + t] + hb * w2[h * 512 + t + 256];
        __syncthreads();
        for (int s = 128; s > 0; s >>= 1) {
            if (t < s) red[t] += red[t + s];
            __syncthreads();
        }
        if (t == 0) biastab[e * 8 + h] = 16.0f / (1.0f + expf(-red[0]));
    }
}

// ---------------- expand bias to [8][64][64] ----------------
__global__ void biasx_kernel(const float* __restrict__ biastab, float* __restrict__ biasx) {
    int h = blockIdx.x >> 6, n = blockIdx.x & 63, m = threadIdx.x;
    int idx = ((n >> 3) - (m >> 3) + 7) * 15 + ((n & 7) - (m & 7) + 7);
    biasx[((size_t)(h * 64 + n)) * 64 + m] = biastab[idx * 8 + h];
}

// ---------------- qkv GEMM per window (M=64/block, 3 wave-rounds) ----------------
// writes q_ws,k_ws (normalized, token-major) and vT_ws [lwin][h][chan32][tok64]
__global__ __launch_bounds__(256, 3) void qkv_kernel(
    const float* __restrict__ x, const ushort* __restrict__ qwb,
    const float* __restrict__ qb, ushort* __restrict__ q_ws,
    ushort* __restrict__ k_ws, ushort* __restrict__ vT_ws,
    int shift, int win0)
{
    __shared__ ushort xs[64 * 256];
    const int t = threadIdx.x;
    const int win = win0 + blockIdx.x, lwin = blockIdx.x;
    const int b = win >> 6, wh = (win >> 3) & 7, ww = win & 7;
    const int w = t >> 6, l = t & 63, lr = l & 15, lg = l >> 4;
    const int aswz = (lr & 7) << 3;
    const f32x4 zf = { 0.f, 0.f, 0.f, 0.f };

    {   // stage rolled window tokens (f32 -> bf16, swizzled)
        int row = t >> 2, seg = t & 3;
        int i = row >> 3, j = row & 7;
        int rr = (wh * 8 + i + shift) & 63;
        int cc = (ww * 8 + j + shift) & 63;
        const float* src = x + ((size_t)(b * 4096 + rr * 64 + cc)) * 256 + seg * 64;
        #pragma unroll
        for (int k8 = 0; k8 < 8; ++k8) {
            float4 v0 = *reinterpret_cast<const float4*>(src + k8 * 8);
            float4 v1 = *reinterpret_cast<const float4*>(src + k8 * 8 + 4);
            int col = seg * 64 + k8 * 8;
            *reinterpret_cast<bf16x8*>(xs + row * 256 + (col ^ ((row & 7) << 3))) = cvt8(v0, v1);
        }
    }
    __syncthreads();

    for (int round = 0; round < 3; ++round) {
        const int colb = round * 256 + w * 64;
        f32x4 acc[4][4];
        #pragma unroll
        for (int mf = 0; mf < 4; ++mf)
            #pragma unroll
            for (int nf = 0; nf < 4; ++nf) acc[mf][nf] = zf;

        for (int kt = 0; kt < 8; ++kt) {
            int k0 = kt * 32 + lg * 8;
            bf16x8 a[4], bfr[4];
            #pragma unroll
            for (int mf = 0; mf < 4; ++mf)
                a[mf] = *reinterpret_cast<const bf16x8*>(xs + (mf * 16 + lr) * 256 + (k0 ^ aswz));
            #pragma unroll
            for (int nf = 0; nf < 4; ++nf)
                bfr[nf] = *reinterpret_cast<const bf16x8*>(qwb + (size_t)(colb + nf * 16 + lr) * 256 + k0);
            #pragma unroll
            for (int mf = 0; mf < 4; ++mf)
                #pragma unroll
                for (int nf = 0; nf < 4; ++nf)
                    acc[mf][nf] = MFMA16(a[mf], bfr[nf], acc[mf][nf]);
        }

        // bias add
        #pragma unroll
        for (int nf = 0; nf < 4; ++nf) {
            float bb = qb[colb + nf * 16 + lr];
            #pragma unroll
            for (int mf = 0; mf < 4; ++mf)
                #pragma unroll
                for (int r = 0; r < 4; ++r) acc[mf][nf][r] += bb;
        }

        if (round < 2) {
            // per-head (32-chan) L2 norm: head pair {nf0,1} and {nf2,3}
            float ss0[4][4], ss1[4][4];
            #pragma unroll
            for (int mf = 0; mf < 4; ++mf)
                #pragma unroll
                for (int r = 0; r < 4; ++r) {
                    ss0[mf][r] = acc[mf][0][r] * acc[mf][0][r] + acc[mf][1][r] * acc[mf][1][r];
                    ss1[mf][r] = acc[mf][2][r] * acc[mf][2][r] + acc[mf][3][r] * acc[mf][3][r];
                }
            #pragma unroll
            for (int m = 1; m < 16; m <<= 1)
                #pragma unroll
                for (int mf = 0; mf < 4; ++mf)
                    #pragma unroll
                    for (int r = 0; r < 4; ++r) {
                        ss0[mf][r] += __shfl_xor(ss0[mf][r], m);
                        ss1[mf][r] += __shfl_xor(ss1[mf][r], m);
                    }
            ushort* dst = (round == 0) ? q_ws : k_ws;
            #pragma unroll
            for (int mf = 0; mf < 4; ++mf)
                #pragma unroll
                for (int r = 0; r < 4; ++r) {
                    float rs0 = 1.0f / (sqrtf(ss0[mf][r]) + 1e-12f);
                    float rs1 = 1.0f / (sqrtf(ss1[mf][r]) + 1e-12f);
                    size_t rowoff = ((size_t)lwin * 64 + mf * 16 + lg * 4 + r) * 256;
                    #pragma unroll
                    for (int nf = 0; nf < 4; ++nf)
                        dst[rowoff + w * 64 + nf * 16 + lr] =
                            f2b(acc[mf][nf][r] * (nf < 2 ? rs0 : rs1));
                }
        } else {
            // v: write transposed [lwin][h][chan][tok]
            #pragma unroll
            for (int nf = 0; nf < 4; ++nf) {
                int h = 2 * w + (nf >> 1);
                int chan = (nf & 1) * 16 + lr;
                ushort* vrow = vT_ws + (((size_t)lwin * 8 + h) * 32 + chan) * 64;
                #pragma unroll
                for (int mf = 0; mf < 4; ++mf)
                    #pragma unroll
                    for (int r = 0; r < 4; ++r)
                        vrow[mf * 16 + lg * 4 + r] = f2b(acc[mf][nf][r]);
            }
        }
    }
}

// ---------------- fused attention (S+softmax+PV) + proj + post-LN + residual ----------------
// one block per window; wave w handles heads {2w, 2w+1} over the FULL 64-token window
__global__ __launch_bounds__(256, 2) void attnproj_kernel(
    const ushort* __restrict__ q_ws, const ushort* __restrict__ k_ws,
    const ushort* __restrict__ vT_ws, const ushort* __restrict__ pwb,
    const float* __restrict__ pb, const float* __restrict__ lsc,
    const float* __restrict__ biasx, const float* __restrict__ n1s,
    const float* __restrict__ n1b, const float* __restrict__ xin,
    float* __restrict__ xout, int shift, int win0)
{
    extern __shared__ ushort sm[];
    ushort* aol  = sm + 4 * 64 * 72;    // [64][256] bf16, swizzled
    float*  outT = (float*)sm;          // [64][264] f32 overlay

    const int t = threadIdx.x;
    const int win = win0 + blockIdx.x, lwin = blockIdx.x;
    const int b = win >> 6, wh = (win >> 3) & 7, ww = win & 7;
    const int w = t >> 6, l = t & 63, lr = l & 15, lg = l >> 4;
    ushort* Pw = sm + w * 64 * 72;      // wave-private P
    const size_t tokbase = (size_t)lwin * 64;
    const f32x4 zf = { 0.f, 0.f, 0.f, 0.f };

    // shift-mask regions
    int regc[4], regr[4][4];
    #pragma unroll
    for (int nf = 0; nf < 4; ++nf) {
        int kc = nf * 16 + lr;
        int pr = wh * 8 + (kc >> 3), pc = ww * 8 + (kc & 7);
        regc[nf] = ((pr < 56) ? 0 : ((pr < 60) ? 1 : 2)) * 3 +
                   ((pc < 56) ? 0 : ((pc < 60) ? 1 : 2));
    }
    #pragma unroll
    for (int mf = 0; mf < 4; ++mf)
        #pragma unroll
        for (int r = 0; r < 4; ++r) {
            int n = mf * 16 + lg * 4 + r;
            int pr = wh * 8 + (n >> 3), pc = ww * 8 + (n & 7);
            regr[mf][r] = ((pr < 56) ? 0 : ((pr < 60) ? 1 : 2)) * 3 +
                          ((pc < 56) ? 0 : ((pc < 60) ? 1 : 2));
        }

    for (int hr = 0; hr < 2; ++hr) {
        const int h = w * 2 + hr;

        // ---- S = q @ k^T (M=64, N=64, K=32) ----
        f32x4 sacc[4][4];
        {
            bf16x8 aq[4], bk[4];
            #pragma unroll
            for (int mf = 0; mf < 4; ++mf)
                aq[mf] = *reinterpret_cast<const bf16x8*>(
                    q_ws + (tokbase + mf * 16 + lr) * 256 + h * 32 + lg * 8);
            #pragma unroll
            for (int nf = 0; nf < 4; ++nf)
                bk[nf] = *reinterpret_cast<const bf16x8*>(
                    k_ws + (tokbase + nf * 16 + lr) * 256 + h * 32 + lg * 8);
            #pragma unroll
            for (int mf = 0; mf < 4; ++mf)
                #pragma unroll
                for (int nf = 0; nf < 4; ++nf)
                    sacc[mf][nf] = MFMA16(aq[mf], bk[nf], zf);
        }

        // ---- scale + bias + mask + softmax (in-register, 16-lane reduce) ----
        const float scale = __expf(fminf(lsc[h], 4.6051702f));
        float mx[4][4], sum[4][4];
        #pragma unroll
        for (int mf = 0; mf < 4; ++mf)
            #pragma unroll
            for (int r = 0; r < 4; ++r) mx[mf][r] = -1e30f;

        #pragma unroll
        for (int nf = 0; nf < 4; ++nf)
            #pragma unroll
            for (int mf = 0; mf < 4; ++mf)
                #pragma unroll
                for (int r = 0; r < 4; ++r) {
                    float v = sacc[mf][nf][r] * scale +
                              biasx[((size_t)(h * 64 + mf * 16 + lg * 4 + r)) * 64 + nf * 16 + lr];
                    if (shift && regc[nf] != regr[mf][r]) v -= 100.0f;
                    sacc[mf][nf][r] = v;
                    mx[mf][r] = fmaxf(mx[mf][r], v);
                }
        #pragma unroll
        for (int m = 1; m < 16; m <<= 1)
            #pragma unroll
            for (int mf = 0; mf < 4; ++mf)
                #pragma unroll
                for (int r = 0; r < 4; ++r) mx[mf][r] = fmaxf(mx[mf][r], __shfl_xor(mx[mf][r], m));

        #pragma unroll
        for (int mf = 0; mf < 4; ++mf)
            #pragma unroll
            for (int r = 0; r < 4; ++r) sum[mf][r] = 0.f;
        #pragma unroll
        for (int nf = 0; nf < 4; ++nf)
            #pragma unroll
            for (int mf = 0; mf < 4; ++mf)
                #pragma unroll
                for (int r = 0; r < 4; ++r) {
                    float e = __expf(sacc[mf][nf][r] - mx[mf][r]);
                    sacc[mf][nf][r] = e;
                    sum[mf][r] += e;
                }
        #pragma unroll
        for (int m = 1; m < 16; m <<= 1)
            #pragma unroll
            for (int mf = 0; mf < 4; ++mf)
                #pragma unroll
                for (int r = 0; r < 4; ++r) sum[mf][r] += __shfl_xor(sum[mf][r], m);

        // unnormalized P -> wave-private LDS
        #pragma unroll
        for (int nf = 0; nf < 4; ++nf)
            #pragma unroll
            for (int mf = 0; mf < 4; ++mf)
                #pragma unroll
                for (int r = 0; r < 4; ++r)
                    Pw[(mf * 16 + lg * 4 + r) * 72 + nf * 16 + lr] = f2b(sacc[mf][nf][r]);

        // ---- PV: M=64, N=32, K=64 ----
        f32x4 oacc[4][2];
        #pragma unroll
        for (int mf = 0; mf < 4; ++mf)
            #pragma unroll
            for (int nf = 0; nf < 2; ++nf) oacc[mf][nf] = zf;
        #pragma unroll
        for (int ks = 0; ks < 2; ++ks) {
            bf16x8 pa[4], bv[2];
            #pragma unroll
            for (int mf = 0; mf < 4; ++mf)
                pa[mf] = *reinterpret_cast<const bf16x8*>(Pw + (mf * 16 + lr) * 72 + ks * 32 + lg * 8);
            #pragma unroll
            for (int nf = 0; nf < 2; ++nf)
                bv[nf] = *reinterpret_cast<const bf16x8*>(
                    vT_ws + (((size_t)lwin * 8 + h) * 32 + nf * 16 + lr) * 64 + ks * 32 + lg * 8);
            #pragma unroll
            for (int mf = 0; mf < 4; ++mf)
                #pragma unroll
                for (int nf = 0; nf < 2; ++nf)
                    oacc[mf][nf] = MFMA16(pa[mf], bv[nf], oacc[mf][nf]);
        }

        // ---- normalized out -> swizzled LDS ao tile ----
        #pragma unroll
        for (int mf = 0; mf < 4; ++mf)
            #pragma unroll
            for (int r = 0; r < 4; ++r) {
                float inv = 1.0f / sum[mf][r];
                int row = mf * 16 + lg * 4 + r;
                #pragma unroll
                for (int nf = 0; nf < 2; ++nf) {
                    int col = h * 32 + nf * 16 + lr;
                    aol[row * 256 + (col ^ ((row & 7) << 3))] = f2b(oacc[mf][nf][r] * inv);
                }
            }
    }
    __syncthreads();

    // ---- proj GEMM: M=64, N=64 (wave slice), K=256 ----
    f32x4 acc[4][4];
    #pragma unroll
    for (int mf = 0; mf < 4; ++mf)
        #pragma unroll
        for (int nf = 0; nf < 4; ++nf) acc[mf][nf] = zf;
    const int aswz = (lr & 7) << 3;
    for (int kt = 0; kt < 8; ++kt) {
        int k0 = kt * 32 + lg * 8;
        bf16x8 a[4], bfr[4];
        #pragma unroll
        for (int mf = 0; mf < 4; ++mf)
            a[mf] = *reinterpret_cast<const bf16x8*>(aol + (mf * 16 + lr) * 256 + (k0 ^ aswz));
        #pragma unroll
        for (int nf = 0; nf < 4; ++nf)
            bfr[nf] = *reinterpret_cast<const bf16x8*>(
                pwb + (size_t)(w * 64 + nf * 16 + lr) * 256 + k0);
        #pragma unroll
        for (int mf = 0; mf < 4; ++mf)
            #pragma unroll
            for (int nf = 0; nf < 4; ++nf)
                acc[mf][nf] = MFMA16(a[mf], bfr[nf], acc[mf][nf]);
    }
    __syncthreads();   // all aol/P reads done; overlay outT

    #pragma unroll
    for (int nf = 0; nf < 4; ++nf) {
        int c = w * 64 + nf * 16 + lr;
        float bb = pb[c];
        #pragma unroll
        for (int mf = 0; mf < 4; ++mf)
            #pragma unroll
            for (int r = 0; r < 4; ++r)
                outT[(mf * 16 + lg * 4 + r) * 264 + c] = acc[mf][nf][r] + bb;
    }
    __syncthreads();

    // ---- LN + un-roll scatter + residual: wave w handles tokens w*16 .. +15 ----
    for (int u = 0; u < 16; ++u) {
        int tk = w * 16 + u;
        float v0 = outT[tk * 264 + l];
        float v1 = outT[tk * 264 + l + 64];
        float v2 = outT[tk * 264 + l + 128];
        float v3 = outT[tk * 264 + l + 192];
        float s = v0 + v1 + v2 + v3, ss = v0 * v0 + v1 * v1 + v2 * v2 + v3 * v3;
        for (int m = 1; m < 64; m <<= 1) { s += __shfl_xor(s, m); ss += __shfl_xor(ss, m); }
        float mean = s * (1.0f / 256.0f);
        float var  = ss * (1.0f / 256.0f) - mean * mean;
        float rs   = rsqrtf(var + 1e-5f);

        int i = tk >> 3, j = tk & 7;
        int pr = (wh * 8 + i + shift) & 63;
        int pc = (ww * 8 + j + shift) & 63;
        size_t gaddr = ((size_t)(b * 4096 + pr * 64 + pc)) * 256;
        xout[gaddr + l]       = xin[gaddr + l]       + (v0 - mean) * rs * n1s[l]       + n1b[l];
        xout[gaddr + l + 64]  = xin[gaddr + l + 64]  + (v1 - mean) * rs * n1s[l + 64]  + n1b[l + 64];
        xout[gaddr + l + 128] = xin[gaddr + l + 128] + (v2 - mean) * rs * n1s[l + 128] + n1b[l + 128];
        xout[gaddr + l + 192] = xin[gaddr + l + 192] + (v3 - mean) * rs * n1s[l + 192] + n1b[l + 192];
    }
}

// ---------------- fused MLP (bf16 MFMA, M=64/block, hid in 4 LDS chunks) ----------------
__global__ __launch_bounds__(256, 2) void mlp_mfma_kernel(
    float* __restrict__ x, const ushort* __restrict__ w1b, const float* __restrict__ b1,
    const ushort* __restrict__ w2b, const float* __restrict__ b2,
    const float* __restrict__ n2s, const float* __restrict__ n2b)
{
    extern __shared__ ushort sm2[];
    ushort* xs = sm2;               // [64][256] bf16, swizzled
    ushort* hc = sm2 + 64 * 256;    // [64][256] bf16, swizzled (current chunk)
    float*  outT = (float*)sm2;     // [64][264] f32 overlay (epilogue)

    const int t = threadIdx.x;
    const size_t tok0 = (size_t)blockIdx.x * 64;
    const int w = t >> 6, l = t & 63, lr = l & 15, lg = l >> 4;
    const int aswz = (lr & 7) << 3;
    const f32x4 zf = { 0.f, 0.f, 0.f, 0.f };

    {
        int row = t >> 2, seg = t & 3;
        const float* src = x + (tok0 + row) * 256 + seg * 64;
        #pragma unroll
        for (int k8 = 0; k8 < 8; ++k8) {
            float4 v0 = *reinterpret_cast<const float4*>(src + k8 * 8);
            float4 v1 = *reinterpret_cast<const float4*>(src + k8 * 8 + 4);
            int col = seg * 64 + k8 * 8;
            *reinterpret_cast<bf16x8*>(xs + row * 256 + (col ^ ((row & 7) << 3))) = cvt8(v0, v1);
        }
    }
    __syncthreads();

    f32x4 acc2[4][4];
    #pragma unroll
    for (int mf = 0; mf < 4; ++mf)
        #pragma unroll
        for (int nf = 0; nf < 4; ++nf) acc2[mf][nf] = zf;

    for (int c = 0; c < 4; ++c) {
        f32x4 acc1[4][4];
        #pragma unroll
        for (int mf = 0; mf < 4; ++mf)
            #pragma unroll
            for (int nf = 0; nf < 4; ++nf) acc1[mf][nf] = zf;

        const int hcol0 = c * 256 + w * 64;
        for (int kt = 0; kt < 8; ++kt) {
            int k0 = kt * 32 + lg * 8;
            bf16x8 a[4], bfr[4];
            #pragma unroll
            for (int mf = 0; mf < 4; ++mf)
                a[mf] = *reinterpret_cast<const bf16x8*>(xs + (mf * 16 + lr) * 256 + (k0 ^ aswz));
            #pragma unroll
            for (int nf = 0; nf < 4; ++nf)
                bfr[nf] = *reinterpret_cast<const bf16x8*>(
                    w1b + (size_t)(hcol0 + nf * 16 + lr) * 256 + k0);
            #pragma unroll
            for (int mf = 0; mf < 4; ++mf)
                #pragma unroll
                for (int nf = 0; nf < 4; ++nf)
                    acc1[mf][nf] = MFMA16(a[mf], bfr[nf], acc1[mf][nf]);
        }

        __syncthreads();

        #pragma unroll
        for (int nf = 0; nf < 4; ++nf) {
            int lcol = w * 64 + nf * 16 + lr;
            float bb = b1[c * 256 + lcol];
            #pragma unroll
            for (int mf = 0; mf < 4; ++mf)
                #pragma unroll
                for (int r = 0; r < 4; ++r) {
                    int hrow = mf * 16 + lg * 4 + r;
                    float pre = acc1[mf][nf][r] + bb;
                    float g = 0.5f * pre * (1.0f + erff(pre * 0.70710678f));
                    hc[hrow * 256 + (lcol ^ ((hrow & 7) << 3))] = f2b(g);
                }
        }
        __syncthreads();

        for (int kt = 0; kt < 8; ++kt) {
            int k0 = kt * 32 + lg * 8;
            bf16x8 a[4], bfr[4];
            #pragma unroll
            for (int mf = 0; mf < 4; ++mf)
                a[mf] = *reinterpret_cast<const bf16x8*>(hc + (mf * 16 + lr) * 256 + (k0 ^ aswz));
            #pragma unroll
            for (int nf = 0; nf < 4; ++nf)
                bfr[nf] = *reinterpret_cast<const bf16x8*>(
                    w2b + (size_t)(w * 64 + nf * 16 + lr) * 1024 + c * 256 + k0);
            #pragma unroll
            for (int mf = 0; mf < 4; ++mf)
                #pragma unroll
                for (int nf = 0; nf < 4; ++nf)
                    acc2[mf][nf] = MFMA16(a[mf], bfr[nf], acc2[mf][nf]);
        }
    }
    __syncthreads();

    #pragma unroll
    for (int nf = 0; nf < 4; ++nf) {
        int cc = w * 64 + nf * 16 + lr;
        float bb = b2[cc];
        #pragma unroll
        for (int mf = 0; mf < 4; ++mf)
            #pragma unroll
            for (int r = 0; r < 4; ++r)
                outT[(mf * 16 + lg * 4 + r) * 264 + cc] = acc2[mf][nf][r] + bb;
    }
    __syncthreads();

    for (int u = 0; u < 16; ++u) {
        int tk = w * 16 + u;
        float v0 = outT[tk * 264 + l];
        float v1 = outT[tk * 264 + l + 64];
        float v2 = outT[tk * 264 + l + 128];
        float v3 = outT[tk * 264 + l + 192];
        float s = v0 + v1 + v2 + v3, ss = v0 * v0 + v1 * v1 + v2 * v2 + v3 * v3;
        for (int m = 1; m < 64; m <<= 1) { s += __shfl_xor(s, m); ss += __shfl_xor(ss, m); }
        float mean = s * (1.0f / 256.0f);
        float var  = ss * (1.0f / 256.0f) - mean * mean;
        float rs   = rsqrtf(var + 1e-5f);
        float* xp = x + (tok0 + tk) * 256;
        xp[l]       += (v0 - mean) * rs * n2s[l]       + n2b[l];
        xp[l + 64]  += (v1 - mean) * rs * n2s[l + 64]  + n2b[l + 64];
        xp[l + 128] += (v2 - mean) * rs * n2s[l + 128] + n2b[l + 128];
        xp[l + 192] += (v3 - mean) * rs * n2s[l + 192] + n2b[l + 192];
    }
}

// ---------------- launcher ----------------
extern "C" void kernel_launch(void* const* d_in, const int* in_sizes, int n_in,
                              void* d_out, int out_size, void* d_ws, size_t ws_size,
                              hipStream_t stream) {
    (void)in_sizes; (void)n_in; (void)out_size; (void)ws_size;
    const float* tokens = (const float*)d_in[0];
    const float* qkv_w  = (const float*)d_in[3];
    const float* qkv_b  = (const float*)d_in[4];
    const float* lsc    = (const float*)d_in[5];
    const float* cw1    = (const float*)d_in[6];
    const float* cb1    = (const float*)d_in[7];
    const float* cw2    = (const float*)d_in[8];
    const float* pw     = (const float*)d_in[9];
    const float* pb     = (const float*)d_in[10];
    const float* n1s    = (const float*)d_in[11];
    const float* n1b    = (const float*)d_in[12];
    const float* mw1    = (const float*)d_in[13];
    const float* mb1    = (const float*)d_in[14];
    const float* mw2    = (const float*)d_in[15];
    const float* mb2    = (const float*)d_in[16];
    const float* n2s    = (const float*)d_in[17];
    const float* n2b    = (const float*)d_in[18];

    float* x = (float*)d_out;

    // workspace layout (all 16B aligned); total ~51.5 MB
    ushort* q_ws  = (ushort*)d_ws;                       // HWIN*64*256 bf16 = 16 MB
    ushort* k_ws  = q_ws + (size_t)HWIN * 64 * 256;      // 16 MB
    ushort* vT_ws = k_ws + (size_t)HWIN * 64 * 256;      // 16 MB
    float*  biastab = (float*)(vT_ws + (size_t)HWIN * 64 * 256);   // 1800 f32
    ushort* pwb   = (ushort*)((char*)biastab + 7680);    // 256 KB
    ushort* w1b   = pwb + 2 * 256 * 256;                 // 1 MB
    ushort* w2b   = w1b + 2 * 1024 * 256;                // 1 MB
    ushort* qwb   = w2b + 2 * 256 * 1024;                // 768 KB
    float*  biasx = (float*)(qwb + 2 * 768 * 256);       // 128 KB

    f2b_kernel<<<dim3(2 * 256 * 256 / 1024),  dim3(256), 0, stream>>>(pwb, pw);
    f2b_kernel<<<dim3(2 * 1024 * 256 / 1024), dim3(256), 0, stream>>>(w1b, mw1);
    f2b_kernel<<<dim3(2 * 256 * 1024 / 1024), dim3(256), 0, stream>>>(w2b, mw2);
    f2b_kernel<<<dim3(2 * 768 * 256 / 1024),  dim3(256), 0, stream>>>(qwb, qkv_w);

    for (int l = 0; l < 2; ++l) {
        const int shift = l ? 4 : 0;
        const float* xsrc = (l == 0) ? tokens : x;
        cpb_kernel<<<dim3(225), dim3(256), 0, stream>>>(
            cw1 + (size_t)l * 1024, cb1 + (size_t)l * 512, cw2 + (size_t)l * 4096, biastab);
        biasx_kernel<<<dim3(512), dim3(64), 0, stream>>>(biastab, biasx);
        for (int half = 0; half < 2; ++half) {
            qkv_kernel<<<dim3(HWIN), dim3(256), 0, stream>>>(
                xsrc, qwb + (size_t)l * 196608, qkv_b + (size_t)l * 768,
                q_ws, k_ws, vT_ws, shift, half * HWIN);
            attnproj_kernel<<<dim3(HWIN), dim3(256), AP_LDS, stream>>>(
                q_ws, k_ws, vT_ws, pwb + (size_t)l * 65536, pb + (size_t)l * 256,
                lsc + (size_t)l * 8, biasx, n1s + (size_t)l * 256, n1b + (size_t)l * 256,
                xsrc, x, shift, half * HWIN);
        }
        mlp_mfma_kernel<<<dim3(NTOK / 64), dim3(256), MLP_LDS, stream>>>(
            x, w1b + (size_t)l * 262144, mb1 + (size_t)l * 1024,
            w2b + (size_t)l * 262144, mb2 + (size_t)l * 256,
            n2s + (size_t)l * 256, n2b + (size_t)l * 256);
    }
}